// Round 5
// baseline (740.820 us; speedup 1.0000x reference)
//
#include <hip/hip_runtime.h>
#include <math.h>

#define D 64
#define K 512

// ---------------------------------------------------------------------------
// numpy pairwise sum of v[i]*v[i], n=64 — exact numpy algorithm
// ---------------------------------------------------------------------------
__device__ __forceinline__ float np_sumsq64(const float* v)
{
#pragma clang fp contract(off)
    float p[64];
#pragma unroll
    for (int i = 0; i < 64; ++i) p[i] = v[i] * v[i];
    float r[8];
#pragma unroll
    for (int j = 0; j < 8; ++j) r[j] = p[j];
#pragma unroll
    for (int b = 8; b < 64; b += 8) {
#pragma unroll
        for (int j = 0; j < 8; ++j) r[j] += p[b + j];
    }
    return ((r[0] + r[1]) + (r[2] + r[3])) + ((r[4] + r[5]) + (r[6] + r[7]));
}

// ---------------------------------------------------------------------------
// Kernel 1: e2[k] = numpy-f32 sum(e_k*e_k); sq[k] = f32 sqrt(cs[k])
// ---------------------------------------------------------------------------
__global__ void vq_prep(const float* __restrict__ emb,
                        const float* __restrict__ cs,
                        float* __restrict__ e2,
                        float* __restrict__ sq)
{
    int k = blockIdx.x * blockDim.x + threadIdx.x;
    if (k >= K) return;
    float er[64];
    const float* ek = emb + (size_t)k * D;
#pragma unroll
    for (int d = 0; d < 64; ++d) er[d] = ek[d];
    e2[k] = np_sumsq64(er);
    sq[k] = (float)sqrt((double)cs[k]);
}

// ---------------------------------------------------------------------------
// Kernel 2 (fused): argmin + gather + STE output + loss partials.
// P=1: one point per thread -> 4096 waves = 16 waves/CU = 4 waves/SIMD,
// doubling latency hiding vs R4 (grid-limited 2 waves/SIMD, VALUBusy 64%).
// Codes read at wave-uniform addresses -> scalar pipe (s_load), FMAs on
// VALU with SGPR operand. Numerics identical to the passing R2/R4 path.
// ---------------------------------------------------------------------------
__global__ __launch_bounds__(256) void vq_main(
    const float* __restrict__ x,
    const float* __restrict__ emb,
    const float* __restrict__ e2,
    const float* __restrict__ sq,
    float* __restrict__ out_q,
    float* __restrict__ out_idx,
    double* __restrict__ partial,
    int N)
{
    int n = blockIdx.x * blockDim.x + threadIdx.x;

    float xr[64];
    if (n < N) {
        const float4* xp = (const float4*)(x + (size_t)n * D);
#pragma unroll
        for (int q = 0; q < 16; ++q) {
            float4 v = xp[q];
            xr[4 * q + 0] = v.x;
            xr[4 * q + 1] = v.y;
            xr[4 * q + 2] = v.z;
            xr[4 * q + 3] = v.w;
        }
    } else {
#pragma unroll
        for (int i = 0; i < 64; ++i) xr[i] = 0.0f;
    }

    float x2 = np_sumsq64(xr);

    float best = INFINITY;
    int   bi = 0;

    const float4* eb = (const float4*)emb;

    for (int j = 0; j < K; j += 2) {
        const float4* r0 = eb + (size_t)j * 16;
        const float4* r1 = r0 + 16;

        float acc0 = 0.0f, acc1 = 0.0f;
#pragma unroll
        for (int k4 = 0; k4 < 16; ++k4) {
            float4 u = r0[k4];
            float4 w = r1[k4];
            int k = 4 * k4;
            acc0 = fmaf(xr[k + 0], u.x, acc0);
            acc0 = fmaf(xr[k + 1], u.y, acc0);
            acc0 = fmaf(xr[k + 2], u.z, acc0);
            acc0 = fmaf(xr[k + 3], u.w, acc0);
            acc1 = fmaf(xr[k + 0], w.x, acc1);
            acc1 = fmaf(xr[k + 1], w.y, acc1);
            acc1 = fmaf(xr[k + 2], w.z, acc1);
            acc1 = fmaf(xr[k + 3], w.w, acc1);
        }

        float q0 = e2[j], q1 = e2[j + 1];
        float s0 = sq[j], s1 = sq[j + 1];
        {
#pragma clang fp contract(off)
            float d0 = ((x2 + q0) - 2.0f * acc0) * s0;
            if (d0 < best) { best = d0; bi = j; }
            float d1 = ((x2 + q1) - 2.0f * acc1) * s1;
            if (d1 < best) { best = d1; bi = j + 1; }
        }
    }

    // ---- fused epilogue: index write, gather, STE output, loss partial ----
    double s = 0.0;
    if (n < N) {
        out_idx[n] = (float)bi;
        const float4* qr = (const float4*)(emb + (size_t)bi * D);
        float4* oq = (float4*)(out_q + (size_t)n * D);
#pragma unroll
        for (int q = 0; q < 16; ++q) {
            float4 q4 = qr[q];
            float xa = xr[4 * q + 0], xb = xr[4 * q + 1];
            float xc = xr[4 * q + 2], xd = xr[4 * q + 3];
            float4 o;
            {
#pragma clang fp contract(off)
                o.x = xa + (q4.x - xa);
                o.y = xb + (q4.y - xb);
                o.z = xc + (q4.z - xc);
                o.w = xd + (q4.w - xd);
            }
            oq[q] = o;
            double dx = (double)q4.x - (double)xa;
            double dy = (double)q4.y - (double)xb;
            double dz = (double)q4.z - (double)xc;
            double dw = (double)q4.w - (double)xd;
            s += dx * dx + dy * dy + dz * dz + dw * dw;
        }
    }

#pragma unroll
    for (int off = 32; off > 0; off >>= 1)
        s += __shfl_down(s, off, 64);

    __shared__ double ls[4];
    if ((threadIdx.x & 63) == 0) ls[threadIdx.x >> 6] = s;
    __syncthreads();
    if (threadIdx.x == 0)
        partial[blockIdx.x] = ls[0] + ls[1] + ls[2] + ls[3];
}

// ---------------------------------------------------------------------------
// Kernel 3: reduce partials -> loss
// ---------------------------------------------------------------------------
__global__ __launch_bounds__(256) void vq_finalize(
    const double* __restrict__ partial,
    float* __restrict__ loss_out,
    int nblk, double inv_count)
{
    double s = 0.0;
    for (int i = threadIdx.x; i < nblk; i += 256) s += partial[i];
#pragma unroll
    for (int off = 32; off > 0; off >>= 1)
        s += __shfl_down(s, off, 64);
    __shared__ double ls[4];
    if ((threadIdx.x & 63) == 0) ls[threadIdx.x >> 6] = s;
    __syncthreads();
    if (threadIdx.x == 0) {
        double total = ls[0] + ls[1] + ls[2] + ls[3];
        loss_out[0] = (float)(0.25 * total * inv_count);
    }
}

// ---------------------------------------------------------------------------
extern "C" void kernel_launch(void* const* d_in, const int* in_sizes, int n_in,
                              void* d_out, int out_size, void* d_ws, size_t ws_size,
                              hipStream_t stream)
{
    const float* x   = (const float*)d_in[0];   // [N, 64]
    const float* emb = (const float*)d_in[1];   // [512, 64]
    const float* cs  = (const float*)d_in[2];   // [512]

    const int N = in_sizes[0] / D;              // 262144

    float* out      = (float*)d_out;
    float* out_q    = out;                      // [N*64]
    float* out_loss = out + (size_t)N * D;      // [1]
    float* out_idx  = out_loss + 1;             // [N]

    // workspace layout
    float*  e2      = (float*)d_ws;                       // 512 f32
    float*  sq      = e2 + K;                             // 512 f32
    double* partial = (double*)((char*)d_ws + 8192);      // per-block f64

    const int nblk = (N + 255) / 256;                     // 1024

    vq_prep<<<(K + 255) / 256, 256, 0, stream>>>(emb, cs, e2, sq);
    vq_main<<<nblk, 256, 0, stream>>>(x, emb, e2, sq,
                                      out_q, out_idx, partial, N);
    vq_finalize<<<1, 256, 0, stream>>>(partial, out_loss, nblk,
                                       1.0 / ((double)N * (double)D));
}

// Round 6
// 670.648 us; speedup vs baseline: 1.1046x; 1.1046x over previous
//
#include <hip/hip_runtime.h>
#include <math.h>

#define D 64
#define K 512
#define P 2              // points per thread (proven no-spill in R4)
#define KL 256           // codes 0..KL-1 via LDS; KL..K-1 via scalar/global

// ---------------------------------------------------------------------------
// numpy pairwise sum of v[i]*v[i], n=64 — exact numpy algorithm
// ---------------------------------------------------------------------------
__device__ __forceinline__ float np_sumsq64(const float* v)
{
#pragma clang fp contract(off)
    float p[64];
#pragma unroll
    for (int i = 0; i < 64; ++i) p[i] = v[i] * v[i];
    float r[8];
#pragma unroll
    for (int j = 0; j < 8; ++j) r[j] = p[j];
#pragma unroll
    for (int b = 8; b < 64; b += 8) {
#pragma unroll
        for (int j = 0; j < 8; ++j) r[j] += p[b + j];
    }
    return ((r[0] + r[1]) + (r[2] + r[3])) + ((r[4] + r[5]) + (r[6] + r[7]));
}

// ---------------------------------------------------------------------------
// Kernel 1: e2[k] = numpy-f32 sum(e_k*e_k); sq[k] = f32 sqrt(cs[k])
// ---------------------------------------------------------------------------
__global__ void vq_prep(const float* __restrict__ emb,
                        const float* __restrict__ cs,
                        float* __restrict__ e2,
                        float* __restrict__ sq)
{
    int k = blockIdx.x * blockDim.x + threadIdx.x;
    if (k >= K) return;
    float er[64];
    const float* ek = emb + (size_t)k * D;
#pragma unroll
    for (int d = 0; d < 64; ++d) er[d] = ek[d];
    e2[k] = np_sumsq64(er);
    sq[k] = (float)sqrt((double)cs[k]);
}

// ---------------------------------------------------------------------------
// Kernel 2 (fused): argmin + gather + STE output + loss partials.
// HYBRID distribution: codes 0..255 from a 64KB LDS tile (ds_read pipe),
// codes 256..511 from global at wave-uniform addresses (scalar pipe).
// The two phases are sequential per wave (ascending-j scan -> strict-<
// argmin stays numpy-exact) but overlap across the 8 waves/CU.
// P=2 amortizes every code read over 2 points. Numerics identical to the
// passing R2/R4 path.
// ---------------------------------------------------------------------------
__global__ __launch_bounds__(256) void vq_main(
    const float* __restrict__ x,
    const float* __restrict__ emb,
    const float* __restrict__ e2,
    const float* __restrict__ sq,
    float* __restrict__ out_q,
    float* __restrict__ out_idx,
    double* __restrict__ partial,
    int N)
{
    __shared__ float se[KL * D];   // 64 KB -> 2 blocks/CU

    int t  = blockIdx.x * blockDim.x + threadIdx.x;
    int n0 = t * P;

    // stage codes 0..KL-1 into LDS, coalesced
    {
        const float4* src = (const float4*)emb;
        float4* dst = (float4*)se;
        for (int i = threadIdx.x; i < KL * D / 4; i += 256)
            dst[i] = src[i];
    }

    float xr[P][64];
#pragma unroll
    for (int p = 0; p < P; ++p) {
        if (n0 + p < N) {
            const float4* xp = (const float4*)(x + (size_t)(n0 + p) * D);
#pragma unroll
            for (int q = 0; q < 16; ++q) {
                float4 v = xp[q];
                xr[p][4 * q + 0] = v.x;
                xr[p][4 * q + 1] = v.y;
                xr[p][4 * q + 2] = v.z;
                xr[p][4 * q + 3] = v.w;
            }
        } else {
#pragma unroll
            for (int i = 0; i < 64; ++i) xr[p][i] = 0.0f;
        }
    }

    float x2[P];
#pragma unroll
    for (int p = 0; p < P; ++p) x2[p] = np_sumsq64(xr[p]);

    float best[P];
    int   bi[P];
#pragma unroll
    for (int p = 0; p < P; ++p) { best[p] = INFINITY; bi[p] = 0; }

    __syncthreads();

    // ---------------- phase A: codes 0..KL-1 from LDS ----------------
    for (int j = 0; j < KL; j += 2) {
        const float* r0 = se + j * D;
        const float* r1 = r0 + D;

        float acc0[P], acc1[P];
#pragma unroll
        for (int p = 0; p < P; ++p) { acc0[p] = 0.0f; acc1[p] = 0.0f; }

#pragma unroll
        for (int k4 = 0; k4 < 16; ++k4) {
            float4 u = *(const float4*)(r0 + 4 * k4);
            float4 w = *(const float4*)(r1 + 4 * k4);
            int k = 4 * k4;
#pragma unroll
            for (int p = 0; p < P; ++p) {
                acc0[p] = fmaf(xr[p][k + 0], u.x, acc0[p]);
                acc0[p] = fmaf(xr[p][k + 1], u.y, acc0[p]);
                acc0[p] = fmaf(xr[p][k + 2], u.z, acc0[p]);
                acc0[p] = fmaf(xr[p][k + 3], u.w, acc0[p]);
                acc1[p] = fmaf(xr[p][k + 0], w.x, acc1[p]);
                acc1[p] = fmaf(xr[p][k + 1], w.y, acc1[p]);
                acc1[p] = fmaf(xr[p][k + 2], w.z, acc1[p]);
                acc1[p] = fmaf(xr[p][k + 3], w.w, acc1[p]);
            }
        }

        float q0 = e2[j], q1 = e2[j + 1];
        float s0 = sq[j], s1 = sq[j + 1];
        {
#pragma clang fp contract(off)
#pragma unroll
            for (int p = 0; p < P; ++p) {
                float d0 = ((x2[p] + q0) - 2.0f * acc0[p]) * s0;
                if (d0 < best[p]) { best[p] = d0; bi[p] = j; }
                float d1 = ((x2[p] + q1) - 2.0f * acc1[p]) * s1;
                if (d1 < best[p]) { best[p] = d1; bi[p] = j + 1; }
            }
        }
    }

    // ------------- phase B: codes KL..K-1 wave-uniform global -------------
    const float4* eb = (const float4*)emb;
    for (int j = KL; j < K; j += 2) {
        const float4* r0 = eb + (size_t)j * 16;
        const float4* r1 = r0 + 16;

        float acc0[P], acc1[P];
#pragma unroll
        for (int p = 0; p < P; ++p) { acc0[p] = 0.0f; acc1[p] = 0.0f; }

#pragma unroll
        for (int k4 = 0; k4 < 16; ++k4) {
            float4 u = r0[k4];
            float4 w = r1[k4];
            int k = 4 * k4;
#pragma unroll
            for (int p = 0; p < P; ++p) {
                acc0[p] = fmaf(xr[p][k + 0], u.x, acc0[p]);
                acc0[p] = fmaf(xr[p][k + 1], u.y, acc0[p]);
                acc0[p] = fmaf(xr[p][k + 2], u.z, acc0[p]);
                acc0[p] = fmaf(xr[p][k + 3], u.w, acc0[p]);
                acc1[p] = fmaf(xr[p][k + 0], w.x, acc1[p]);
                acc1[p] = fmaf(xr[p][k + 1], w.y, acc1[p]);
                acc1[p] = fmaf(xr[p][k + 2], w.z, acc1[p]);
                acc1[p] = fmaf(xr[p][k + 3], w.w, acc1[p]);
            }
        }

        float q0 = e2[j], q1 = e2[j + 1];
        float s0 = sq[j], s1 = sq[j + 1];
        {
#pragma clang fp contract(off)
#pragma unroll
            for (int p = 0; p < P; ++p) {
                float d0 = ((x2[p] + q0) - 2.0f * acc0[p]) * s0;
                if (d0 < best[p]) { best[p] = d0; bi[p] = j; }
                float d1 = ((x2[p] + q1) - 2.0f * acc1[p]) * s1;
                if (d1 < best[p]) { best[p] = d1; bi[p] = j + 1; }
            }
        }
    }

    // ---- fused epilogue: index write, gather, STE output, loss partial ----
    double s = 0.0;
#pragma unroll
    for (int p = 0; p < P; ++p) {
        if (n0 + p >= N) continue;
        out_idx[n0 + p] = (float)bi[p];
        const float4* qr = (const float4*)(emb + (size_t)bi[p] * D);
        float4* oq = (float4*)(out_q + (size_t)(n0 + p) * D);
#pragma unroll
        for (int q = 0; q < 16; ++q) {
            float4 q4 = qr[q];
            float xa = xr[p][4 * q + 0], xb = xr[p][4 * q + 1];
            float xc = xr[p][4 * q + 2], xd = xr[p][4 * q + 3];
            float4 o;
            {
#pragma clang fp contract(off)
                o.x = xa + (q4.x - xa);
                o.y = xb + (q4.y - xb);
                o.z = xc + (q4.z - xc);
                o.w = xd + (q4.w - xd);
            }
            oq[q] = o;
            double dx = (double)q4.x - (double)xa;
            double dy = (double)q4.y - (double)xb;
            double dz = (double)q4.z - (double)xc;
            double dw = (double)q4.w - (double)xd;
            s += dx * dx + dy * dy + dz * dz + dw * dw;
        }
    }

#pragma unroll
    for (int off = 32; off > 0; off >>= 1)
        s += __shfl_down(s, off, 64);

    __shared__ double ls[4];
    if ((threadIdx.x & 63) == 0) ls[threadIdx.x >> 6] = s;
    __syncthreads();
    if (threadIdx.x == 0)
        partial[blockIdx.x] = ls[0] + ls[1] + ls[2] + ls[3];
}

// ---------------------------------------------------------------------------
// Kernel 3: reduce partials -> loss
// ---------------------------------------------------------------------------
__global__ __launch_bounds__(256) void vq_finalize(
    const double* __restrict__ partial,
    float* __restrict__ loss_out,
    int nblk, double inv_count)
{
    double s = 0.0;
    for (int i = threadIdx.x; i < nblk; i += 256) s += partial[i];
#pragma unroll
    for (int off = 32; off > 0; off >>= 1)
        s += __shfl_down(s, off, 64);
    __shared__ double ls[4];
    if ((threadIdx.x & 63) == 0) ls[threadIdx.x >> 6] = s;
    __syncthreads();
    if (threadIdx.x == 0) {
        double total = ls[0] + ls[1] + ls[2] + ls[3];
        loss_out[0] = (float)(0.25 * total * inv_count);
    }
}

// ---------------------------------------------------------------------------
extern "C" void kernel_launch(void* const* d_in, const int* in_sizes, int n_in,
                              void* d_out, int out_size, void* d_ws, size_t ws_size,
                              hipStream_t stream)
{
    const float* x   = (const float*)d_in[0];   // [N, 64]
    const float* emb = (const float*)d_in[1];   // [512, 64]
    const float* cs  = (const float*)d_in[2];   // [512]

    const int N = in_sizes[0] / D;              // 262144

    float* out      = (float*)d_out;
    float* out_q    = out;                      // [N*64]
    float* out_loss = out + (size_t)N * D;      // [1]
    float* out_idx  = out_loss + 1;             // [N]

    // workspace layout
    float*  e2      = (float*)d_ws;                       // 512 f32
    float*  sq      = e2 + K;                             // 512 f32
    double* partial = (double*)((char*)d_ws + 8192);      // per-block f64

    const int nthreads = (N + P - 1) / P;                 // 131072
    const int nblk     = (nthreads + 255) / 256;          // 512

    vq_prep<<<(K + 255) / 256, 256, 0, stream>>>(emb, cs, e2, sq);
    vq_main<<<nblk, 256, 0, stream>>>(x, emb, e2, sq,
                                      out_q, out_idx, partial, N);
    vq_finalize<<<1, 256, 0, stream>>>(partial, out_loss, nblk,
                                       1.0 / ((double)N * (double)D));
}

// Round 9
// 286.732 us; speedup vs baseline: 2.5837x; 2.3389x over previous
//
#include <hip/hip_runtime.h>
#include <math.h>

#define D 64
#define K 512
#define GAP_EPS 0.02f

typedef __attribute__((ext_vector_type(8))) short short8;
typedef __attribute__((ext_vector_type(4))) float f32x4;

// ---------- workspace layout (all offsets 256-aligned) ----------
#define WS_E2   256
#define WS_SQ   2304
#define WS_BP   4352
#define WS_WL   135424
#define WS_PART 1184000

__device__ __forceinline__ unsigned short f32_to_bf16_rne(float f)
{
    unsigned int u = __float_as_uint(f);
    unsigned int r = (u + 0x7FFFu + ((u >> 16) & 1u)) >> 16;
    return (unsigned short)r;
}
__device__ __forceinline__ float bf16_to_f32(unsigned short h)
{
    return __uint_as_float(((unsigned int)h) << 16);
}

// numpy pairwise sum of v[i]*v[i], n=64 — exact numpy algorithm
__device__ __forceinline__ float np_sumsq64(const float* v)
{
#pragma clang fp contract(off)
    float p[64];
#pragma unroll
    for (int i = 0; i < 64; ++i) p[i] = v[i] * v[i];
    float r[8];
#pragma unroll
    for (int j = 0; j < 8; ++j) r[j] = p[j];
#pragma unroll
    for (int b = 8; b < 64; b += 8) {
#pragma unroll
        for (int j = 0; j < 8; ++j) r[j] += p[b + j];
    }
    return ((r[0] + r[1]) + (r[2] + r[3])) + ((r[4] + r[5]) + (r[6] + r[7]));
}

// ---------------------------------------------------------------------------
// Kernel 1: pack codebook bf16 splits into MFMA B-fragment order; np-exact
// e2/sq; zero worklist counter.
// Bp index: ((((chunk*2+sB)*16+ctl)*2+kc)*512) + lane*8 + j
//   code = chunk*256 + ctl*16 + (lane&15); d = kc*32 + (lane>>4)*8 + j
// ---------------------------------------------------------------------------
__global__ __launch_bounds__(256) void vq_pack_prep(
    const float* __restrict__ emb,
    const float* __restrict__ cs,
    unsigned short* __restrict__ Bp,
    float* __restrict__ e2,
    float* __restrict__ sq,
    int* __restrict__ cnt)
{
    int i = blockIdx.x * blockDim.x + threadIdx.x;
    if (i < 65536) {
        int j    = i & 7;
        int lane = (i >> 3) & 63;
        int kc   = (i >> 9) & 1;
        int ctl  = (i >> 10) & 15;
        int sB   = (i >> 14) & 1;
        int chunk = i >> 15;
        int code = chunk * 256 + ctl * 16 + (lane & 15);
        int d    = kc * 32 + (lane >> 4) * 8 + j;
        float v = emb[code * 64 + d];
        unsigned short b0 = f32_to_bf16_rne(v);
        unsigned short outv;
        if (sB == 0) outv = b0;
        else         outv = f32_to_bf16_rne(v - bf16_to_f32(b0));
        Bp[i] = outv;
    } else if (i < 66048) {
        int k = i - 65536;
        float er[64];
        const float* ek = emb + (size_t)k * D;
#pragma unroll
        for (int d = 0; d < 64; ++d) er[d] = ek[d];
        e2[k] = np_sumsq64(er);
        sq[k] = (float)sqrt((double)cs[k]);
    } else if (i == 66048) {
        *cnt = 0;
    }
}

// ---------------------------------------------------------------------------
// Kernel 2: MFMA screen. Block = 4 waves, 32 points/wave (2 row-tiles).
// C/D layout (m89): col(code)=lane&15, row(point)=quad*4+reg; x2 for acc[r]
// fetched via __shfl from lane quad*4+r (R8 fix).
// R9 FIX: stage the FULL 64KB chunk (4096 float4, it<16) — R7/R8 staged only
// the lower 32KB, so the sB=1 residual fragments (offset 32KB) were poison.
// ---------------------------------------------------------------------------
__global__ __launch_bounds__(256) void vq_screen(
    const float* __restrict__ x,
    const float* __restrict__ e2g,
    const float* __restrict__ sqg,
    const unsigned short* __restrict__ Bp,
    float* __restrict__ out_idx,
    int* __restrict__ wl,
    int* __restrict__ cnt)
{
    __shared__ unsigned short BpS[32768];   // 64 KB chunk
    __shared__ float e2s[512];
    __shared__ float sqs[512];

    const int wave = threadIdx.x >> 6;
    const int lane = threadIdx.x & 63;
    const int quad = lane >> 4;
    const int n16  = lane & 15;
    const int n0   = blockIdx.x * 128 + wave * 32;

    e2s[threadIdx.x]       = e2g[threadIdx.x];
    e2s[threadIdx.x + 256] = e2g[threadIdx.x + 256];
    sqs[threadIdx.x]       = sqg[threadIdx.x];
    sqs[threadIdx.x + 256] = sqg[threadIdx.x + 256];

    // ---- A fragments: lane loads row m=n16 of each row-tile ----
    float xa[2][2][8];
#pragma unroll
    for (int rt = 0; rt < 2; ++rt) {
#pragma unroll
        for (int kc = 0; kc < 2; ++kc) {
            const float* src = x + (size_t)(n0 + rt * 16 + n16) * 64
                               + kc * 32 + quad * 8;
            float4 v0 = *(const float4*)(src);
            float4 v1 = *(const float4*)(src + 4);
            xa[rt][kc][0] = v0.x; xa[rt][kc][1] = v0.y;
            xa[rt][kc][2] = v0.z; xa[rt][kc][3] = v0.w;
            xa[rt][kc][4] = v1.x; xa[rt][kc][5] = v1.y;
            xa[rt][kc][6] = v1.z; xa[rt][kc][7] = v1.w;
        }
    }

    // ||x||^2 of point n16 (full 64 dims after cross-quad reduce)
    float x2v[2];
#pragma unroll
    for (int rt = 0; rt < 2; ++rt) {
        float s = 0.0f;
#pragma unroll
        for (int kc = 0; kc < 2; ++kc)
#pragma unroll
            for (int j = 0; j < 8; ++j)
                s = fmaf(xa[rt][kc][j], xa[rt][kc][j], s);
        s += __shfl_xor(s, 16, 64);
        s += __shfl_xor(s, 32, 64);
        x2v[rt] = s;
    }

    // x2 for accumulator row r is point quad*4+r -> fetch from lane quad*4+r
    float x2p[2][4];
#pragma unroll
    for (int rt = 0; rt < 2; ++rt)
#pragma unroll
        for (int r = 0; r < 4; ++r)
            x2p[rt][r] = __shfl(x2v[rt], quad * 4 + r, 64);

    short8 A0[2][2], A1[2][2];
#pragma unroll
    for (int rt = 0; rt < 2; ++rt)
#pragma unroll
        for (int kc = 0; kc < 2; ++kc)
#pragma unroll
            for (int j = 0; j < 8; ++j) {
                float v = xa[rt][kc][j];
                unsigned short b0 = f32_to_bf16_rne(v);
                unsigned short b1 = f32_to_bf16_rne(v - bf16_to_f32(b0));
                A0[rt][kc][j] = (short)b0;
                A1[rt][kc][j] = (short)b1;
            }

    float d1[2][4], d2[2][4];
    int   i1[2][4], i2[2][4];
#pragma unroll
    for (int rt = 0; rt < 2; ++rt)
#pragma unroll
        for (int r = 0; r < 4; ++r) {
            d1[rt][r] = INFINITY; d2[rt][r] = INFINITY;
            i1[rt][r] = 0;        i2[rt][r] = 0;
        }

    for (int chunk = 0; chunk < 2; ++chunk) {
        __syncthreads();
        {   // stage FULL 64KB chunk: 4096 float4, 16 per thread (R9 fix)
            const float4* src = (const float4*)(Bp + chunk * 32768);
            float4* dst = (float4*)BpS;
#pragma unroll
            for (int it = 0; it < 16; ++it)
                dst[threadIdx.x + it * 256] = src[threadIdx.x + it * 256];
        }
        __syncthreads();

        for (int ctl = 0; ctl < 16; ++ctl) {
            const short8 B00 = *(const short8*)(BpS + ((0 * 16 + ctl) * 2 + 0) * 512 + lane * 8);
            const short8 B01 = *(const short8*)(BpS + ((0 * 16 + ctl) * 2 + 1) * 512 + lane * 8);
            const short8 B10 = *(const short8*)(BpS + ((1 * 16 + ctl) * 2 + 0) * 512 + lane * 8);
            const short8 B11 = *(const short8*)(BpS + ((1 * 16 + ctl) * 2 + 1) * 512 + lane * 8);

            int c = chunk * 256 + ctl * 16 + n16;
            float e2c = e2s[c];
            float sqc = sqs[c];

#pragma unroll
            for (int rt = 0; rt < 2; ++rt) {
                f32x4 acc = {0.0f, 0.0f, 0.0f, 0.0f};
                acc = __builtin_amdgcn_mfma_f32_16x16x32_bf16(A0[rt][0], B00, acc, 0, 0, 0);
                acc = __builtin_amdgcn_mfma_f32_16x16x32_bf16(A0[rt][1], B01, acc, 0, 0, 0);
                acc = __builtin_amdgcn_mfma_f32_16x16x32_bf16(A0[rt][0], B10, acc, 0, 0, 0);
                acc = __builtin_amdgcn_mfma_f32_16x16x32_bf16(A0[rt][1], B11, acc, 0, 0, 0);
                acc = __builtin_amdgcn_mfma_f32_16x16x32_bf16(A1[rt][0], B00, acc, 0, 0, 0);
                acc = __builtin_amdgcn_mfma_f32_16x16x32_bf16(A1[rt][1], B01, acc, 0, 0, 0);

#pragma unroll
                for (int r = 0; r < 4; ++r) {
                    float dist = ((x2p[rt][r] + e2c) - 2.0f * acc[r]) * sqc;
                    if (dist < d1[rt][r]) {
                        d2[rt][r] = d1[rt][r]; i2[rt][r] = i1[rt][r];
                        d1[rt][r] = dist;      i1[rt][r] = c;
                    } else if (dist < d2[rt][r]) {
                        d2[rt][r] = dist;      i2[rt][r] = c;
                    }
                }
            }
        }
    }

    // butterfly-merge best-2 across the 16 lanes of each quad
#pragma unroll
    for (int rt = 0; rt < 2; ++rt)
#pragma unroll
        for (int r = 0; r < 4; ++r) {
            float ad1 = d1[rt][r], ad2 = d2[rt][r];
            int   ai1 = i1[rt][r], ai2 = i2[rt][r];
#pragma unroll
            for (int w = 1; w < 16; w <<= 1) {
                float od1 = __shfl_xor(ad1, w, 64);
                float od2 = __shfl_xor(ad2, w, 64);
                int   oi1 = __shfl_xor(ai1, w, 64);
                int   oi2 = __shfl_xor(ai2, w, 64);
                if (od1 < ad1) {
                    float nd2 = (ad1 < od2) ? ad1 : od2;
                    int   ni2 = (ad1 < od2) ? ai1 : oi2;
                    ad2 = nd2; ai2 = ni2; ad1 = od1; ai1 = oi1;
                } else if (od1 < ad2) {
                    ad2 = od1; ai2 = oi1;
                }
            }
            d1[rt][r] = ad1; i1[rt][r] = ai1; d2[rt][r] = ad2; i2[rt][r] = ai2;
        }

    if (n16 == 0) {
#pragma unroll
        for (int rt = 0; rt < 2; ++rt)
#pragma unroll
            for (int r = 0; r < 4; ++r) {
                int p = n0 + rt * 16 + quad * 4 + r;
                out_idx[p] = (float)i1[rt][r];
                if (d2[rt][r] - d1[rt][r] <= GAP_EPS) {
                    int slot = atomicAdd(cnt, 1);
                    wl[slot] = p;
                }
            }
    }
}

// ---------------------------------------------------------------------------
// Kernel 3: exact numpy-f32 rescan of flagged points. One wave per point,
// lane-per-code (8 codes/lane, ascending), tie -> lower index.
// ---------------------------------------------------------------------------
__global__ __launch_bounds__(256) void vq_exact(
    const float* __restrict__ x,
    const float* __restrict__ emb,
    const float* __restrict__ e2,
    const float* __restrict__ sq,
    const int* __restrict__ wl,
    const int* __restrict__ cnt,
    float* __restrict__ out_idx)
{
    const int lane = threadIdx.x & 63;
    const int gw   = blockIdx.x * 4 + (threadIdx.x >> 6);
    const int nw   = gridDim.x * 4;
    const int cv   = *cnt;

    for (int w = gw; w < cv; w += nw) {
        int p = wl[w];
        const float* xrow = x + (size_t)p * 64;
        float row[64];
#pragma unroll
        for (int i = 0; i < 16; ++i) {
            float4 v = ((const float4*)xrow)[i];
            row[4 * i + 0] = v.x; row[4 * i + 1] = v.y;
            row[4 * i + 2] = v.z; row[4 * i + 3] = v.w;
        }
        float x2 = np_sumsq64(row);

        float bd = INFINITY;
        int   bc = 0;
        for (int t = 0; t < 8; ++t) {
            int c = t * 64 + lane;
            const float* er = emb + (size_t)c * 64;
            float acc = 0.0f;
#pragma unroll
            for (int d = 0; d < 64; ++d)
                acc = fmaf(row[d], er[d], acc);
            float dist;
            {
#pragma clang fp contract(off)
                dist = ((x2 + e2[c]) - 2.0f * acc) * sq[c];
            }
            if (dist < bd) { bd = dist; bc = c; }
        }
#pragma unroll
        for (int wd = 1; wd < 64; wd <<= 1) {
            float od = __shfl_xor(bd, wd, 64);
            int   oc = __shfl_xor(bc, wd, 64);
            if (od < bd || (od == bd && oc < bc)) { bd = od; bc = oc; }
        }
        if (lane == 0) out_idx[p] = (float)bc;
    }
}

// ---------------------------------------------------------------------------
// Kernel 4: gather chosen code, STE output, fp64 per-block loss partials
// ---------------------------------------------------------------------------
__global__ __launch_bounds__(256) void vq_epilogue(
    const float* __restrict__ x,
    const float* __restrict__ emb,
    const float* __restrict__ idx_f,
    float* __restrict__ out_q,
    double* __restrict__ partial)
{
    int i = blockIdx.x * blockDim.x + threadIdx.x;   // float4 index
    int n  = i >> 4;
    int d4 = i & 15;

    int bi = (int)idx_f[n];
    float4 q4 = *(const float4*)(emb + (size_t)bi * D + 4 * d4);
    float4 x4 = ((const float4*)x)[i];

    float4 o;
    {
#pragma clang fp contract(off)
        o.x = x4.x + (q4.x - x4.x);
        o.y = x4.y + (q4.y - x4.y);
        o.z = x4.z + (q4.z - x4.z);
        o.w = x4.w + (q4.w - x4.w);
    }
    ((float4*)out_q)[i] = o;

    double dx = (double)q4.x - (double)x4.x;
    double dy = (double)q4.y - (double)x4.y;
    double dz = (double)q4.z - (double)x4.z;
    double dw = (double)q4.w - (double)x4.w;
    double s = dx * dx + dy * dy + dz * dz + dw * dw;

#pragma unroll
    for (int off = 32; off > 0; off >>= 1)
        s += __shfl_down(s, off, 64);

    __shared__ double ls[4];
    if ((threadIdx.x & 63) == 0) ls[threadIdx.x >> 6] = s;
    __syncthreads();
    if (threadIdx.x == 0)
        partial[blockIdx.x] = ls[0] + ls[1] + ls[2] + ls[3];
}

// ---------------------------------------------------------------------------
// Kernel 5: reduce partials -> loss
// ---------------------------------------------------------------------------
__global__ __launch_bounds__(256) void vq_finalize(
    const double* __restrict__ partial,
    float* __restrict__ loss_out,
    int nblk, double inv_count)
{
    double s = 0.0;
    for (int i = threadIdx.x; i < nblk; i += 256) s += partial[i];
#pragma unroll
    for (int off = 32; off > 0; off >>= 1)
        s += __shfl_down(s, off, 64);
    __shared__ double ls[4];
    if ((threadIdx.x & 63) == 0) ls[threadIdx.x >> 6] = s;
    __syncthreads();
    if (threadIdx.x == 0) {
        double total = ls[0] + ls[1] + ls[2] + ls[3];
        loss_out[0] = (float)(0.25 * total * inv_count);
    }
}

// ---------------------------------------------------------------------------
extern "C" void kernel_launch(void* const* d_in, const int* in_sizes, int n_in,
                              void* d_out, int out_size, void* d_ws, size_t ws_size,
                              hipStream_t stream)
{
    const float* x   = (const float*)d_in[0];   // [N, 64]
    const float* emb = (const float*)d_in[1];   // [512, 64]
    const float* cs  = (const float*)d_in[2];   // [512]

    const int N = in_sizes[0] / D;              // 262144

    float* out      = (float*)d_out;
    float* out_q    = out;                      // [N*64]
    float* out_loss = out + (size_t)N * D;      // [1]
    float* out_idx  = out_loss + 1;             // [N]

    char* ws = (char*)d_ws;
    int*            cnt     = (int*)ws;
    float*          e2      = (float*)(ws + WS_E2);
    float*          sq      = (float*)(ws + WS_SQ);
    unsigned short* Bp      = (unsigned short*)(ws + WS_BP);
    int*            wl      = (int*)(ws + WS_WL);
    double*         partial = (double*)(ws + WS_PART);

    const int nblk_ep = (N * D / 4) / 256;      // 16384

    vq_pack_prep<<<259, 256, 0, stream>>>(emb, cs, Bp, e2, sq, cnt);
    vq_screen<<<N / 128, 256, 0, stream>>>(x, e2, sq, Bp, out_idx, wl, cnt);
    vq_exact<<<512, 256, 0, stream>>>(x, emb, e2, sq, wl, cnt, out_idx);
    vq_epilogue<<<nblk_ep, 256, 0, stream>>>(x, emb, out_idx, out_q, partial);
    vq_finalize<<<1, 256, 0, stream>>>(partial, out_loss, nblk_ep,
                                       1.0 / ((double)N * (double)D));
}

// Round 10
// 212.834 us; speedup vs baseline: 3.4807x; 1.3472x over previous
//
#include <hip/hip_runtime.h>
#include <math.h>

#define D 64
#define K 512

typedef __attribute__((ext_vector_type(8))) short short8;
typedef __attribute__((ext_vector_type(4))) float f32x4;

// ---------- workspace layout (256-aligned) ----------
// 0       : int cnt
// 256     : float e2[512]     (np-exact, for vq_exact)
// 2304    : float sq[512]     (np-exact, for vq_exact)
// 4352    : float e2sq[512]   (e2*sq, screen only)
// 6400    : float tsq[512]    (2*sq, screen only)
// 8448    : ushort Bp[65536]  (bf16 splits, 32KB-chunk frag order, 128KB)
// 139520  : int wl[N]         (1MB)
// 1188096 : double partial[2048]   (screen per-block loss)
// 1204480 : double partial2[N]     (exact per-flagged-point loss)
#define WS_E2    256
#define WS_SQ    2304
#define WS_E2SQ  4352
#define WS_TSQ   6400
#define WS_BP    8448
#define WS_WL    139520
#define WS_PART  1188096
#define WS_PART2 1204480

#define KEYMASK 0xFFFFFE00u   // drop 9 mantissa bits, keep 9 index bits

__device__ __forceinline__ unsigned short f32_to_bf16_rne(float f)
{
    unsigned int u = __float_as_uint(f);
    unsigned int r = (u + 0x7FFFu + ((u >> 16) & 1u)) >> 16;
    return (unsigned short)r;
}
__device__ __forceinline__ float bf16_to_f32(unsigned short h)
{
    return __uint_as_float(((unsigned int)h) << 16);
}

// numpy pairwise sum of v[i]*v[i], n=64 — exact numpy algorithm
__device__ __forceinline__ float np_sumsq64(const float* v)
{
#pragma clang fp contract(off)
    float p[64];
#pragma unroll
    for (int i = 0; i < 64; ++i) p[i] = v[i] * v[i];
    float r[8];
#pragma unroll
    for (int j = 0; j < 8; ++j) r[j] = p[j];
#pragma unroll
    for (int b = 8; b < 64; b += 8) {
#pragma unroll
        for (int j = 0; j < 8; ++j) r[j] += p[b + j];
    }
    return ((r[0] + r[1]) + (r[2] + r[3])) + ((r[4] + r[5]) + (r[6] + r[7]));
}

// ---------------------------------------------------------------------------
// Kernel 1: pack codebook bf16 splits (32KB-chunk order: 4 chunks x 128
// codes); np-exact e2/sq; screen-side e2sq/tsq; zero worklist counter.
// Bp linear index i = chunk<<14 | sB<<13 | ctl<<10 | kc<<9 | lane<<3 | j
//   code = chunk*128 + ctl*16 + (lane&15); d = kc*32 + (lane>>4)*8 + j
// ---------------------------------------------------------------------------
__global__ __launch_bounds__(256) void vq_pack_prep(
    const float* __restrict__ emb,
    const float* __restrict__ cs,
    unsigned short* __restrict__ Bp,
    float* __restrict__ e2,
    float* __restrict__ sq,
    float* __restrict__ e2sq,
    float* __restrict__ tsq,
    int* __restrict__ cnt)
{
    int i = blockIdx.x * blockDim.x + threadIdx.x;
    if (i < 65536) {
        int j    = i & 7;
        int lane = (i >> 3) & 63;
        int kc   = (i >> 9) & 1;
        int ctl  = (i >> 10) & 7;
        int sB   = (i >> 13) & 1;
        int chunk = (i >> 14) & 3;
        int code = chunk * 128 + ctl * 16 + (lane & 15);
        int d    = kc * 32 + (lane >> 4) * 8 + j;
        float v = emb[code * 64 + d];
        unsigned short b0 = f32_to_bf16_rne(v);
        Bp[i] = (sB == 0) ? b0 : f32_to_bf16_rne(v - bf16_to_f32(b0));
    } else if (i < 66048) {
        int k = i - 65536;
        float er[64];
        const float* ek = emb + (size_t)k * D;
#pragma unroll
        for (int d = 0; d < 64; ++d) er[d] = ek[d];
        float e2v = np_sumsq64(er);
        float sqv = (float)sqrt((double)cs[k]);
        e2[k]   = e2v;
        sq[k]   = sqv;
        e2sq[k] = e2v * sqv;     // screen-only, a-few-ulp error is in margin
        tsq[k]  = 2.0f * sqv;    // exact
    } else if (i == 66048) {
        *cnt = 0;
    }
}

// ---------------------------------------------------------------------------
// Kernel 2: MFMA screen + fused epilogue for certified points.
// 32KB chunks -> LDS ~37KB -> 4 blocks/CU (R9 was 2). Key-packed best-2:
// key = (bits(max(dist,0)) & KEYMASK) | code  -> min/max/min tracking, index
// rides in low 9 bits (quantized-equal keys always flagged: quantum<margin).
// dist = fma(x2/2, 2sq, e2sq) - fma(2sq, acc) — 2 VALU/pair.
// Certified points: gather e[bi], STE write, fp64 loss — x refetched (L2-hot)
// so xa registers die early. Flagged: screen writes placeholder idx only;
// vq_exact rewrites idx + out_q row + loss.
// ---------------------------------------------------------------------------
__global__ __launch_bounds__(256) void vq_screen(
    const float* __restrict__ x,
    const float* __restrict__ emb,
    const float* __restrict__ e2sqg,
    const float* __restrict__ tsqg,
    const unsigned short* __restrict__ Bp,
    float* __restrict__ out_q,
    float* __restrict__ out_idx,
    int* __restrict__ wl,
    int* __restrict__ cnt,
    double* __restrict__ partial)
{
    __shared__ unsigned short BpS[16384];   // 32 KB chunk
    __shared__ float e2sqs[512];
    __shared__ float tsqs[512];
    __shared__ double ls[4];

    const int wave = threadIdx.x >> 6;
    const int lane = threadIdx.x & 63;
    const int quad = lane >> 4;
    const int n16  = lane & 15;
    const int n0   = blockIdx.x * 128 + wave * 32;

    e2sqs[threadIdx.x]       = e2sqg[threadIdx.x];
    e2sqs[threadIdx.x + 256] = e2sqg[threadIdx.x + 256];
    tsqs[threadIdx.x]        = tsqg[threadIdx.x];
    tsqs[threadIdx.x + 256]  = tsqg[threadIdx.x + 256];

    // ---- A fragments (bf16 2-term split) + x2; xa not kept ----
    short8 A0[2][2], A1[2][2];
    float x2h[2][4];
#pragma unroll
    for (int rt = 0; rt < 2; ++rt) {
        float s = 0.0f;
#pragma unroll
        for (int kc = 0; kc < 2; ++kc) {
            const float* src = x + (size_t)(n0 + rt * 16 + n16) * 64
                               + kc * 32 + quad * 8;
            float4 v0 = *(const float4*)(src);
            float4 v1 = *(const float4*)(src + 4);
            float xv[8] = {v0.x, v0.y, v0.z, v0.w, v1.x, v1.y, v1.z, v1.w};
#pragma unroll
            for (int j = 0; j < 8; ++j) {
                float v = xv[j];
                unsigned short b0 = f32_to_bf16_rne(v);
                unsigned short b1 = f32_to_bf16_rne(v - bf16_to_f32(b0));
                A0[rt][kc][j] = (short)b0;
                A1[rt][kc][j] = (short)b1;
                s = fmaf(v, v, s);
            }
        }
        s += __shfl_xor(s, 16, 64);
        s += __shfl_xor(s, 32, 64);
        // acc[r] belongs to point quad*4+r (m89 C/D layout) -> fetch its x2/2
#pragma unroll
        for (int r = 0; r < 4; ++r)
            x2h[rt][r] = 0.5f * __shfl(s, quad * 4 + r, 64);
    }

    unsigned k1[2][4], k2[2][4];
#pragma unroll
    for (int rt = 0; rt < 2; ++rt)
#pragma unroll
        for (int r = 0; r < 4; ++r) { k1[rt][r] = 0xFFFFFFFFu; k2[rt][r] = 0xFFFFFFFFu; }

    for (int chunk = 0; chunk < 4; ++chunk) {
        __syncthreads();
        {   // stage 32KB chunk: 2048 float4, 8 per thread
            const float4* src = (const float4*)(Bp + chunk * 16384);
            float4* dst = (float4*)BpS;
#pragma unroll
            for (int it = 0; it < 8; ++it)
                dst[threadIdx.x + it * 256] = src[threadIdx.x + it * 256];
        }
        __syncthreads();

        for (int ctl = 0; ctl < 8; ++ctl) {
            const short8 B00 = *(const short8*)(BpS + (ctl * 2 + 0) * 512 + lane * 8);
            const short8 B01 = *(const short8*)(BpS + (ctl * 2 + 1) * 512 + lane * 8);
            const short8 B10 = *(const short8*)(BpS + ((8 + ctl) * 2 + 0) * 512 + lane * 8);
            const short8 B11 = *(const short8*)(BpS + ((8 + ctl) * 2 + 1) * 512 + lane * 8);

            int c = chunk * 128 + ctl * 16 + n16;
            float e2sqc = e2sqs[c];
            float tsqc  = tsqs[c];

#pragma unroll
            for (int rt = 0; rt < 2; ++rt) {
                f32x4 acc = {0.0f, 0.0f, 0.0f, 0.0f};
                acc = __builtin_amdgcn_mfma_f32_16x16x32_bf16(A0[rt][0], B00, acc, 0, 0, 0);
                acc = __builtin_amdgcn_mfma_f32_16x16x32_bf16(A0[rt][1], B01, acc, 0, 0, 0);
                acc = __builtin_amdgcn_mfma_f32_16x16x32_bf16(A0[rt][0], B10, acc, 0, 0, 0);
                acc = __builtin_amdgcn_mfma_f32_16x16x32_bf16(A0[rt][1], B11, acc, 0, 0, 0);
                acc = __builtin_amdgcn_mfma_f32_16x16x32_bf16(A1[rt][0], B00, acc, 0, 0, 0);
                acc = __builtin_amdgcn_mfma_f32_16x16x32_bf16(A1[rt][1], B01, acc, 0, 0, 0);

#pragma unroll
                for (int r = 0; r < 4; ++r) {
                    float dist = fmaf(x2h[rt][r], tsqc, e2sqc);
                    dist = fmaf(-tsqc, acc[r], dist);
                    dist = fmaxf(dist, 0.0f);
                    unsigned key = (__float_as_uint(dist) & KEYMASK) | (unsigned)c;
                    unsigned a1 = k1[rt][r];
                    unsigned mx = a1 > key ? a1 : key;
                    k1[rt][r] = a1 < key ? a1 : key;
                    k2[rt][r] = k2[rt][r] < mx ? k2[rt][r] : mx;
                }
            }
        }
    }

    // merge best-2 across the 16 lanes of each quad (uint keys)
#pragma unroll
    for (int rt = 0; rt < 2; ++rt)
#pragma unroll
        for (int r = 0; r < 4; ++r) {
            unsigned a1 = k1[rt][r], a2 = k2[rt][r];
#pragma unroll
            for (int w = 1; w < 16; w <<= 1) {
                unsigned o1 = (unsigned)__shfl_xor((int)a1, w, 64);
                unsigned o2 = (unsigned)__shfl_xor((int)a2, w, 64);
                unsigned mx  = a1 > o1 ? a1 : o1;
                a1 = a1 < o1 ? a1 : o1;
                unsigned mn2 = a2 < o2 ? a2 : o2;
                a2 = mn2 < mx ? mn2 : mx;
            }
            k1[rt][r] = a1; k2[rt][r] = a2;
        }

    // flags, index writes, worklist
    unsigned pk[2][4];
#pragma unroll
    for (int rt = 0; rt < 2; ++rt)
#pragma unroll
        for (int r = 0; r < 4; ++r) {
            float d1f = __uint_as_float(k1[rt][r] & KEYMASK);
            float d2f = __uint_as_float(k2[rt][r] & KEYMASK);
            int   i1  = (int)(k1[rt][r] & 0x1FFu);
            int   flg = (d2f - d1f) <= (0.01f + 2.0e-4f * d2f);
            pk[rt][r] = (unsigned)i1 | (flg ? 0x8000u : 0u);
            if (n16 == 0) {
                int p = n0 + rt * 16 + quad * 4 + r;
                out_idx[p] = (float)i1;
                if (flg) { int slot = atomicAdd(cnt, 1); wl[slot] = p; }
            }
        }

    // fused epilogue for certified points: broadcast (bi,flag) to the 4
    // lanes holding each point's x-slice, gather, STE, fp64 loss
    int src = (n16 >> 2) * 16 + n16;   // any lane of quad n16>>2 has the merge
    double s = 0.0;
#pragma unroll
    for (int rt = 0; rt < 2; ++rt) {
        unsigned p0 = (unsigned)__shfl((int)pk[rt][0], src, 64);
        unsigned p1 = (unsigned)__shfl((int)pk[rt][1], src, 64);
        unsigned p2 = (unsigned)__shfl((int)pk[rt][2], src, 64);
        unsigned p3 = (unsigned)__shfl((int)pk[rt][3], src, 64);
        int rr = n16 & 3;
        unsigned pm = (rr == 0) ? p0 : (rr == 1) ? p1 : (rr == 2) ? p2 : p3;
        int bim = (int)(pm & 0x1FFu);
        int flg = (int)((pm >> 15) & 1u);
        if (!flg) {
            int prow = n0 + rt * 16 + n16;
#pragma unroll
            for (int kc = 0; kc < 2; ++kc) {
                const float* xs = x   + (size_t)prow * 64 + kc * 32 + quad * 8;
                const float* es = emb + (size_t)bim  * 64 + kc * 32 + quad * 8;
                float4 xv0 = *(const float4*)(xs);
                float4 xv1 = *(const float4*)(xs + 4);
                float4 ev0 = *(const float4*)(es);
                float4 ev1 = *(const float4*)(es + 4);
                float4 o0, o1;
                float t0, t1, t2, t3, t4, t5, t6, t7;
                {
#pragma clang fp contract(off)
                    t0 = ev0.x - xv0.x; o0.x = xv0.x + t0;
                    t1 = ev0.y - xv0.y; o0.y = xv0.y + t1;
                    t2 = ev0.z - xv0.z; o0.z = xv0.z + t2;
                    t3 = ev0.w - xv0.w; o0.w = xv0.w + t3;
                    t4 = ev1.x - xv1.x; o1.x = xv1.x + t4;
                    t5 = ev1.y - xv1.y; o1.y = xv1.y + t5;
                    t6 = ev1.z - xv1.z; o1.z = xv1.z + t6;
                    t7 = ev1.w - xv1.w; o1.w = xv1.w + t7;
                }
                float* od = out_q + (size_t)prow * 64 + kc * 32 + quad * 8;
                *(float4*)(od)     = o0;
                *(float4*)(od + 4) = o1;
                s += (double)t0 * t0 + (double)t1 * t1
                   + (double)t2 * t2 + (double)t3 * t3
                   + (double)t4 * t4 + (double)t5 * t5
                   + (double)t6 * t6 + (double)t7 * t7;
            }
        }
    }

#pragma unroll
    for (int off = 32; off > 0; off >>= 1)
        s += __shfl_down(s, off, 64);
    if (lane == 0) ls[wave] = s;
    __syncthreads();
    if (threadIdx.x == 0)
        partial[blockIdx.x] = ls[0] + ls[1] + ls[2] + ls[3];
}

// ---------------------------------------------------------------------------
// Kernel 3: np-exact rescan of flagged points (R9-proven core) + their
// index, STE row, and loss contribution.
// ---------------------------------------------------------------------------
__global__ __launch_bounds__(256) void vq_exact(
    const float* __restrict__ x,
    const float* __restrict__ emb,
    const float* __restrict__ e2,
    const float* __restrict__ sq,
    const int* __restrict__ wl,
    const int* __restrict__ cnt,
    float* __restrict__ out_idx,
    float* __restrict__ out_q,
    double* __restrict__ partial2)
{
    const int lane = threadIdx.x & 63;
    const int gw   = blockIdx.x * 4 + (threadIdx.x >> 6);
    const int nw   = gridDim.x * 4;
    const int cv   = *cnt;

    for (int w = gw; w < cv; w += nw) {
        int p = wl[w];
        const float* xrow = x + (size_t)p * 64;
        float row[64];
#pragma unroll
        for (int i = 0; i < 16; ++i) {
            float4 v = ((const float4*)xrow)[i];
            row[4 * i + 0] = v.x; row[4 * i + 1] = v.y;
            row[4 * i + 2] = v.z; row[4 * i + 3] = v.w;
        }
        float x2 = np_sumsq64(row);

        float bd = INFINITY;
        int   bc = 0;
        for (int t = 0; t < 8; ++t) {
            int c = t * 64 + lane;
            const float* er = emb + (size_t)c * 64;
            float acc = 0.0f;
#pragma unroll
            for (int d = 0; d < 64; ++d)
                acc = fmaf(row[d], er[d], acc);
            float dist;
            {
#pragma clang fp contract(off)
                dist = ((x2 + e2[c]) - 2.0f * acc) * sq[c];
            }
            if (dist < bd) { bd = dist; bc = c; }
        }
#pragma unroll
        for (int wd = 1; wd < 64; wd <<= 1) {
            float od = __shfl_xor(bd, wd, 64);
            int   oc = __shfl_xor(bc, wd, 64);
            if (od < bd || (od == bd && oc < bc)) { bd = od; bc = oc; }
        }
        if (lane == 0) out_idx[p] = (float)bc;

        float xv = x[(size_t)p * 64 + lane];
        float qv = emb[(size_t)bc * 64 + lane];
        float t, o;
        {
#pragma clang fp contract(off)
            t = qv - xv;
            o = xv + t;
        }
        out_q[(size_t)p * 64 + lane] = o;
        double dd = (double)t * (double)t;
#pragma unroll
        for (int off = 32; off > 0; off >>= 1)
            dd += __shfl_down(dd, off, 64);
        if (lane == 0) partial2[w] = dd;
    }
}

// ---------------------------------------------------------------------------
// Kernel 4: reduce partials -> loss
// ---------------------------------------------------------------------------
__global__ __launch_bounds__(256) void vq_finalize(
    const double* __restrict__ partial,
    const double* __restrict__ partial2,
    const int* __restrict__ cnt,
    float* __restrict__ loss_out,
    int nblk, double inv_count)
{
    double s = 0.0;
    for (int i = threadIdx.x; i < nblk; i += 256) s += partial[i];
    int cv = *cnt;
    for (int w = threadIdx.x; w < cv; w += 256) s += partial2[w];
#pragma unroll
    for (int off = 32; off > 0; off >>= 1)
        s += __shfl_down(s, off, 64);
    __shared__ double ls[4];
    if ((threadIdx.x & 63) == 0) ls[threadIdx.x >> 6] = s;
    __syncthreads();
    if (threadIdx.x == 0) {
        double total = ls[0] + ls[1] + ls[2] + ls[3];
        loss_out[0] = (float)(0.25 * total * inv_count);
    }
}

// ---------------------------------------------------------------------------
extern "C" void kernel_launch(void* const* d_in, const int* in_sizes, int n_in,
                              void* d_out, int out_size, void* d_ws, size_t ws_size,
                              hipStream_t stream)
{
    const float* x   = (const float*)d_in[0];   // [N, 64]
    const float* emb = (const float*)d_in[1];   // [512, 64]
    const float* cs  = (const float*)d_in[2];   // [512]

    const int N = in_sizes[0] / D;              // 262144

    float* out      = (float*)d_out;
    float* out_q    = out;                      // [N*64]
    float* out_loss = out + (size_t)N * D;      // [1]
    float* out_idx  = out_loss + 1;             // [N]

    char* ws = (char*)d_ws;
    int*            cnt      = (int*)ws;
    float*          e2       = (float*)(ws + WS_E2);
    float*          sq       = (float*)(ws + WS_SQ);
    float*          e2sq     = (float*)(ws + WS_E2SQ);
    float*          tsq      = (float*)(ws + WS_TSQ);
    unsigned short* Bp       = (unsigned short*)(ws + WS_BP);
    int*            wl       = (int*)(ws + WS_WL);
    double*         partial  = (double*)(ws + WS_PART);
    double*         partial2 = (double*)(ws + WS_PART2);

    const int nblk_screen = N / 128;            // 2048

    vq_pack_prep<<<259, 256, 0, stream>>>(emb, cs, Bp, e2, sq, e2sq, tsq, cnt);
    vq_screen<<<nblk_screen, 256, 0, stream>>>(x, emb, e2sq, tsq, Bp,
                                               out_q, out_idx, wl, cnt, partial);
    vq_exact<<<512, 256, 0, stream>>>(x, emb, e2, sq, wl, cnt,
                                      out_idx, out_q, partial2);
    vq_finalize<<<1, 256, 0, stream>>>(partial, partial2, cnt, out_loss,
                                       nblk_screen, 1.0 / ((double)N * (double)D));
}